// Round 4
// baseline (182.696 us; speedup 1.0000x reference)
//
#include <hip/hip_runtime.h>
#include <hip/hip_bf16.h>
#include <math.h>

// B=2, S=2048, D=1024, H=16, Dh=64.
// Q = x@Wq.T + bq ; KV = x@Wv.T + bv (reference bug: K uses value proj).
// Head split: col -> (ii = col>>4 [dim], h = col&15 [head]).
// out[b, s, h*64 + ii] = attn[b,h,s,ii], fp32.

typedef __bf16 bf16x8 __attribute__((ext_vector_type(8)));
typedef float  f32x4  __attribute__((ext_vector_type(4)));
typedef short  s16x4  __attribute__((ext_vector_type(4)));
typedef unsigned short ushort_t;
typedef unsigned short us8 __attribute__((ext_vector_type(8)));

// 0.125 (1/sqrt(64)) * log2(e): folded into Qh so softmax uses exp2 directly.
#define QSCALE 0.1803368801111204f

__device__ __forceinline__ unsigned short f2bf(float f) {
  unsigned int u = __builtin_bit_cast(unsigned int, f);
  u += 0x7fffu + ((u >> 16) & 1u);  // RNE
  return (unsigned short)(u >> 16);
}

// pack two f32 -> bf16x2 dword (a in low half), round-half-up
__device__ __forceinline__ unsigned int pk2(float a, float b) {
  unsigned int ua = __builtin_bit_cast(unsigned int, a) + 0x8000u;
  unsigned int ub = __builtin_bit_cast(unsigned int, b) + 0x8000u;
  return (ua >> 16) | (ub & 0xffff0000u);
}

// single-instruction pack (RNE): lo -> low half, hi -> high half
__device__ __forceinline__ unsigned int cvtpk(float lo, float hi) {
  unsigned int r;
  asm("v_cvt_pk_bf16_f32 %0, %1, %2" : "=v"(r) : "v"(lo), "v"(hi));
  return r;
}

__device__ __forceinline__ void gl_lds16(const void* g, void* l) {
  __builtin_amdgcn_global_load_lds(
      (const __attribute__((address_space(1))) unsigned int*)g,
      (__attribute__((address_space(3))) unsigned int*)l, 16, 0, 0);
}

__device__ __forceinline__ f32x4 mfma_k32(bf16x8 a, bf16x8 b, f32x4 c) {
  return __builtin_amdgcn_mfma_f32_16x16x32_bf16(a, b, c, 0, 0, 0);
}
// K=16 bf16 MFMA: A k-mapping (quad*4+j) == C/D row mapping (quad*4+r), so the
// exp'd S^T accumulator packs directly into PV A-fragments (no LDS round-trip).
__device__ __forceinline__ f32x4 mfma_k16(s16x4 a, s16x4 b, f32x4 c) {
  return __builtin_amdgcn_mfma_f32_16x16x16bf16_1k(a, b, c, 0, 0, 0);
}

// One launch converts x (1048576 float4), Wq (262144), Wv (262144) into the
// contiguous bf16 region [xbf | wqbf | wvbf] in ws.
__global__ __launch_bounds__(256) void cvt3_kernel(const float4* __restrict__ x,
                                                   const float4* __restrict__ wq,
                                                   const float4* __restrict__ wv,
                                                   ushort4* __restrict__ dst) {
  const int i = blockIdx.x * 256 + threadIdx.x;
  const float4 v = (i < 1048576) ? x[i]
                 : (i < 1310720) ? wq[i - 1048576]
                                 : wv[i - 1310720];
  ushort4 o;
  o.x = f2bf(v.x); o.y = f2bf(v.y); o.z = f2bf(v.z); o.w = f2bf(v.w);
  dst[i] = o;
}

// ---------------- Projection GEMM, head-grouped columns ---------------------------
// R8: BN=64 (one head per block) -> grid 32x16x2 = 1024 blocks = 4 blocks/CU
// (was 2): the proj kernel was latency-starved at 2 resident blocks.
// z=0: Q (scaled). z=1: KV; epilogue transposes the block's 1-head tile
// through LDS and writes KVt directly.
__global__ __launch_bounds__(256) void proj_kernel(
    const ushort_t* __restrict__ X,     // [4096][1024] bf16
    const ushort_t* __restrict__ Wqm,
    const ushort_t* __restrict__ Wvm,
    const float*    __restrict__ bq,
    const float*    __restrict__ bv,
    ushort_t* __restrict__ Qh,          // [2][16][2048][64] (scaled by QSCALE)
    ushort_t* __restrict__ KVh,         // [2][16][2048][64]
    ushort_t* __restrict__ KVt)         // [2][16][64][2048]
{
  __shared__ __align__(16) unsigned char lds[24576];   // A 16KB | B 8KB
  const int tid = threadIdx.x;
  const int w  = tid >> 6;
  const int l  = tid & 63;
  const int lq = l >> 4;      // quad
  const int ll = l & 15;
  const bool isQ = (blockIdx.z == 0);
  const ushort_t* Wmat = isQ ? Wqm : Wvm;
  const float*    bias = isQ ? bq  : bv;
  const int m0 = blockIdx.x * 128;
  const int by = blockIdx.y;          // head 0..15
  const int wm = w * 32;              // wave's 32 output rows

  f32x4 acc[2][4] = {};

  for (int k0 = 0; k0 < 1024; k0 += 64) {
    __syncthreads();
#pragma unroll
    for (int t = 0; t < 4; ++t) {     // A tile: 128 rows x 64 k, 16 segs
      const int seg = w * 4 + t;
      const int r = seg * 8 + (l >> 3);
      const int cd = (l & 7) ^ (r & 7);
      gl_lds16(X + (size_t)(m0 + r) * 1024 + k0 + cd * 8, lds + seg * 1024);
    }
#pragma unroll
    for (int t = 0; t < 2; ++t) {     // B tile: 64 cols (head by) x 64 k, 8 segs
      const int seg = w * 2 + t;
      const int r = seg * 8 + (l >> 3);            // ii = r (one head)
      const int cd = (l & 7) ^ (r & 7);
      const int wrow = (r << 4) | by;              // W row for col (ii=r, h=by)
      gl_lds16(Wmat + (size_t)wrow * 1024 + k0 + cd * 8, lds + 16384 + seg * 1024);
    }
    __syncthreads();
#pragma unroll
    for (int kb = 0; kb < 2; ++kb) {
      const int kc = kb * 4 + lq;
      bf16x8 af[2], bfr[4];
#pragma unroll
      for (int mi = 0; mi < 2; ++mi) {
        const int m = wm + mi * 16 + ll;
        af[mi] = *(const bf16x8*)(lds + m * 128 + ((kc ^ (m & 7)) * 16));
      }
#pragma unroll
      for (int ni = 0; ni < 4; ++ni) {
        const int n = ni * 16 + ll;
        bfr[ni] = *(const bf16x8*)(lds + 16384 + n * 128 + ((kc ^ (n & 7)) * 16));
      }
#pragma unroll
      for (int mi = 0; mi < 2; ++mi)
#pragma unroll
        for (int ni = 0; ni < 4; ++ni)
          acc[mi][ni] = mfma_k32(af[mi], bfr[ni], acc[mi][ni]);
    }
  }

  const int hh = by;                  // global head (block-uniform)
  const int b  = m0 >> 11;            // batch (block-uniform; 128 | 2048)
  const int sbase = m0 & 2047;

  if (isQ) {
#pragma unroll
    for (int ni = 0; ni < 4; ++ni) {
      const int ii = ni * 16 + ll;
      const float bb = bias[(ii << 4) | hh];
#pragma unroll
      for (int mi = 0; mi < 2; ++mi)
#pragma unroll
        for (int r = 0; r < 4; ++r) {
          const int s = sbase + wm + mi * 16 + lq * 4 + r;
          const float v = acc[mi][ni][r] + bb;
          Qh[(((size_t)(b * 16 + hh)) * 2048 + s) * 64 + ii] = f2bf(v * QSCALE);
        }
    }
  } else {
    __syncthreads();   // staging LDS no longer needed; reuse for transpose
#pragma unroll
    for (int ni = 0; ni < 4; ++ni) {
      const int ii = ni * 16 + ll;
      const float bb = bias[(ii << 4) | hh];
#pragma unroll
      for (int mi = 0; mi < 2; ++mi) {
        const float v0 = acc[mi][ni][0] + bb;
        const float v1 = acc[mi][ni][1] + bb;
        const float v2 = acc[mi][ni][2] + bb;
        const float v3 = acc[mi][ni][3] + bb;
        const unsigned int u01 = pk2(v0, v1);
        const unsigned int u23 = pk2(v2, v3);
        // KVh stores (coalesced per lane in ii)
        const int sl = wm + mi * 16 + lq * 4;
        const size_t kb0 = (((size_t)(b * 16 + hh)) * 2048 + sbase + sl) * 64 + ii;
        KVh[kb0]       = (ushort_t)(u01 & 0xffffu);
        KVh[kb0 + 64]  = (ushort_t)(u01 >> 16);
        KVh[kb0 + 128] = (ushort_t)(u23 & 0xffffu);
        KVh[kb0 + 192] = (ushort_t)(u23 >> 16);
        // LDS transpose write: granule g holds s_loc = 4g..4g+3 for row ii
        const int g = w * 8 + mi * 4 + lq;              // 0..31
        const int pc = (g >> 1) ^ ll;
        *(uint2*)(lds + ii * 256 + pc * 16 + (g & 1) * 8) =
            make_uint2(u01, u23);
      }
    }
    __syncthreads();
    // Read rows of [ii][s 0..127] and store KVt coalesced (16B per thread)
    const int ii2 = tid >> 2;            // 0..63
    const int cbase = (tid & 3) * 4;
    ushort_t* dst = KVt + (((size_t)(b * 16 + by)) * 64 + ii2) * 2048 + sbase;
#pragma unroll
    for (int cc = 0; cc < 4; ++cc) {
      const int c = cbase + cc;
      const int pc = c ^ (ii2 & 15);
      const us8 v = *(const us8*)(lds + ii2 * 256 + pc * 16);
      *(us8*)(dst + c * 8) = v;
    }
  }
}

// ---------------- Flash attention: split-keys, 2-wave blocks ----------------------
// R8: the LDS pipe was the most-loaded resource (~46%: 16 b128 + 32 b64 per
// wave-kt + 4.2M conflict cycles). Split the KEY range across the block's 2
// waves instead of the q range: each wave computes all 64 q over its own
// 64-key half, so every K A-frag read feeds 4 q-columns (was 2) and every V
// B-frag read feeds 4 -> K reads 8 b128, V reads 16 b64 per wave-kt (halved).
// Bonus: wave w stages exactly the K rows it reads (segs w*8+t = rows
// w*64..), so K-ready/K-free need no cross-wave barrier -> 2 barriers/kt
// (V-free at top, V-ready before PV). One-time cross-wave O/l reduction
// through LDS at the end.
// 128 thr / 2 waves; block = 64 q-rows; LDS: K 16KB + Vt 16KB = 32KB.
__global__ __launch_bounds__(128, 2) void attn_kernel(
    const ushort_t* __restrict__ Qh,
    const ushort_t* __restrict__ KVh,
    const ushort_t* __restrict__ KVt,
    float* __restrict__ out)
{
  __shared__ __align__(16) unsigned char sm[32768];
  const int tid = threadIdx.x;
  const int w  = tid >> 6;
  const int l  = tid & 63;
  const int quad = l >> 4;
  const int ll = l & 15;
  const int bid = blockIdx.x;
  const int bh = ((bid & 7) << 2) | (bid >> 8);   // 4 heads per XCD (L2 locality)
  const int qt = (bid >> 3) & 31;
  const int b = bh >> 4, h = bh & 15;
  const int qw = qt * 64;                         // block's 64 q-rows
  const ushort_t* Qhead  = Qh  + (size_t)bh * (2048 * 64);
  const ushort_t* Khead  = KVh + (size_t)bh * (2048 * 64);
  const ushort_t* Vthead = KVt + (size_t)bh * (64 * 2048);

  // Loop-invariant Q fragments, 4 q-columns (B-operand of S^T: n=q, k=d)
  bf16x8 qf[4][2];
#pragma unroll
  for (int c = 0; c < 4; ++c)
#pragma unroll
    for (int kb = 0; kb < 2; ++kb)
      qf[c][kb] = *(const bf16x8*)(Qhead + (size_t)(qw + c * 16 + ll) * 64 +
                                   kb * 32 + quad * 8);

  f32x4 O[4][4] = {};
  float l_run[4] = {0.f, 0.f, 0.f, 0.f};

  // Prologue: issue K(0) (8 gl_lds / wave; wave w stages its own rows w*64..)
  __builtin_amdgcn_sched_barrier(0);
#pragma unroll
  for (int t = 0; t < 8; ++t) {
    const int seg = w * 8 + t;
    const int r = seg * 8 + (l >> 3);
    const int cd = (l & 7) ^ (r & 7);
    gl_lds16(Khead + (size_t)r * 64 + cd * 8, sm + seg * 1024);
  }

  for (int kt = 0; kt < 16; ++kt) {
    const int sk0 = kt * 128;
    // V buffer about to be overwritten: previous PV's ds_reads must be retired.
    asm volatile("s_waitcnt lgkmcnt(0)" ::: "memory");
    __builtin_amdgcn_sched_barrier(0);
    __builtin_amdgcn_s_barrier();                // barrier A: V buf free
    __builtin_amdgcn_sched_barrier(0);
#pragma unroll
    for (int t = 0; t < 8; ++t) {                // issue V^T(kt) [64 d][128 keys]
      const int seg = w * 8 + t;
      const int d = seg * 4 + (l >> 4);
      const int c8 = (l & 15) ^ (d & 15);        // logical 8-key chunk for phys slot
      gl_lds16(Vthead + (size_t)d * 2048 + sk0 + c8 * 8, sm + 16384 + seg * 1024);
    }
    // Own K(kt) landed (only the 8 newest — V(kt) — may remain in flight).
    // No barrier: this wave reads only the K rows it staged itself.
    asm volatile("s_waitcnt vmcnt(8)" ::: "memory");
    __builtin_amdgcn_sched_barrier(0);

    // S^T = K @ Q^T over this wave's 64 keys: each A-read feeds 4 q-columns
    f32x4 Sa[4][4] = {};
#pragma unroll
    for (int kb = 0; kb < 2; ++kb) {
      const int kc = kb * 4 + quad;
#pragma unroll
      for (int ni = 0; ni < 4; ++ni) {
        const int n = w * 64 + ni * 16 + ll;
        const bf16x8 ak = *(const bf16x8*)(sm + n * 128 + ((kc ^ (n & 7)) * 16));
        Sa[0][ni] = mfma_k32(ak, qf[0][kb], Sa[0][ni]);
        Sa[1][ni] = mfma_k32(ak, qf[1][kb], Sa[1][ni]);
        Sa[2][ni] = mfma_k32(ak, qf[2][kb], Sa[2][ni]);
        Sa[3][ni] = mfma_k32(ak, qf[3][kb], Sa[3][ni]);
      }
    }

    // Own K reads retired before own K(kt+1) overwrite (wave-local; no barrier).
    asm volatile("s_waitcnt lgkmcnt(0)" ::: "memory");
    __builtin_amdgcn_sched_barrier(0);
    if (kt < 15) {                               // issue K(kt+1); hides under exp+PV
      const int sk1 = sk0 + 128;
#pragma unroll
      for (int t = 0; t < 8; ++t) {
        const int seg = w * 8 + t;
        const int r = seg * 8 + (l >> 3);
        const int cd = (l & 7) ^ (r & 7);
        gl_lds16(Khead + (size_t)(sk1 + r) * 64 + cd * 8, sm + seg * 1024);
      }
    }

    // p = exp2(S), pack straight into PV A-fragments (C row map == A k map).
    s16x4 pk[4][4];
#pragma unroll
    for (int c = 0; c < 4; ++c) {
      float ps = 0.f;
#pragma unroll
      for (int ni = 0; ni < 4; ++ni) {
        const float p0 = __builtin_amdgcn_exp2f(Sa[c][ni][0]);
        const float p1 = __builtin_amdgcn_exp2f(Sa[c][ni][1]);
        const float p2 = __builtin_amdgcn_exp2f(Sa[c][ni][2]);
        const float p3 = __builtin_amdgcn_exp2f(Sa[c][ni][3]);
        ps += (p0 + p1) + (p2 + p3);
        const uint2 uu = make_uint2(cvtpk(p0, p1), cvtpk(p2, p3));
        pk[c][ni] = __builtin_bit_cast(s16x4, uu);
      }
      l_run[c] += ps;   // cross-lane reduce deferred to the epilogue (linear)
    }

    // V(kt) landed for this wave's loads; barrier so BOTH waves' halves landed.
    if (kt < 15) { asm volatile("s_waitcnt vmcnt(8)" ::: "memory"); }
    else         { asm volatile("s_waitcnt vmcnt(0)" ::: "memory"); }
    __builtin_amdgcn_sched_barrier(0);
    __builtin_amdgcn_s_barrier();                // barrier B: V(kt) fully landed
    __builtin_amdgcn_sched_barrier(0);

    // O += P @ V over this wave's 64 keys: each B-read feeds 4 q-columns
#pragma unroll
    for (int ni = 0; ni < 4; ++ni) {
      const int cb = w * 8 + 2 * ni + (quad >> 1);   // logical 8-key chunk
#pragma unroll
      for (int no = 0; no < 4; ++no) {
        const int row = no * 16 + ll;                // d
        const s16x4 bv = *(const s16x4*)(sm + 16384 + row * 256 +
                                         ((cb ^ ll) * 16) + (quad & 1) * 8);
        O[0][no] = mfma_k16(pk[0][ni], bv, O[0][no]);
        O[1][no] = mfma_k16(pk[1][ni], bv, O[1][no]);
        O[2][no] = mfma_k16(pk[2][ni], bv, O[2][no]);
        O[3][no] = mfma_k16(pk[3][ni], bv, O[3][no]);
      }
    }
  }

  // ---- cross-wave reduction: wave w owns output cols {2w, 2w+1} ----
  asm volatile("s_waitcnt lgkmcnt(0)" ::: "memory");   // PV reads retired
  __builtin_amdgcn_sched_barrier(0);
  __builtin_amdgcn_s_barrier();
  __builtin_amdgcn_sched_barrier(0);
  // write partials for the cols the OTHER wave stores
#pragma unroll
  for (int j = 0; j < 2; ++j) {
    const int c = (1 - w) * 2 + j;
#pragma unroll
    for (int no = 0; no < 4; ++no)
      *(f32x4*)(sm + c * 4096 + no * 1024 + l * 16) = O[c][no];
    *(float*)(sm + 16384 + c * 256 + l * 4) = l_run[c];
  }
  asm volatile("s_waitcnt lgkmcnt(0)" ::: "memory");   // partials visible
  __builtin_amdgcn_sched_barrier(0);
  __builtin_amdgcn_s_barrier();
  __builtin_amdgcn_sched_barrier(0);
#pragma unroll
  for (int j = 0; j < 2; ++j) {
    const int c = 2 * w + j;
#pragma unroll
    for (int no = 0; no < 4; ++no)
      O[c][no] += *(const f32x4*)(sm + c * 4096 + no * 1024 + l * 16);
    float s = l_run[c] + *(const float*)(sm + 16384 + c * 256 + l * 4);
    s += __shfl_xor(s, 16);
    s += __shfl_xor(s, 32);
    const float inv = 1.f / s;
    float invr[4];
#pragma unroll
    for (int r = 0; r < 4; ++r)
      invr[r] = __shfl(inv, (l & 48) + ((l & 48) >> 2) + r);  // q=quad*4+r's sum
    float* op = out + ((size_t)(b * 2048) + qw + c * 16) * 1024 + h * 64;
#pragma unroll
    for (int no = 0; no < 4; ++no)
#pragma unroll
      for (int r = 0; r < 4; ++r) {
        const int q = quad * 4 + r;
        op[(size_t)q * 1024 + no * 16 + ll] = O[c][no][r] * invr[r];
      }
  }
}

extern "C" void kernel_launch(void* const* d_in, const int* in_sizes, int n_in,
                              void* d_out, int out_size, void* d_ws, size_t ws_size,
                              hipStream_t stream) {
  const float* x  = (const float*)d_in[0];
  const float* Wq = (const float*)d_in[1];
  const float* bq = (const float*)d_in[2];
  const float* Wv = (const float*)d_in[3];
  const float* bv = (const float*)d_in[4];
  float* out = (float*)d_out;
  char* ws = (char*)d_ws;

  ushort_t* xbf  = (ushort_t*)(ws);              //  8 MB
  ushort_t* wqbf = (ushort_t*)(ws + 8388608);    //  2 MB
  ushort_t* wvbf = (ushort_t*)(ws + 10485760);   //  2 MB
  ushort_t* Qh   = (ushort_t*)(ws + 12582912);   //  8 MB [2][16][2048][64]
  ushort_t* KVh  = (ushort_t*)(ws + 20971520);   //  8 MB [2][16][2048][64]
  ushort_t* KVt  = (ushort_t*)(ws + 29360128);   //  8 MB [2][16][64][2048]

  cvt3_kernel<<<6144, 256, 0, stream>>>((const float4*)x, (const float4*)Wq,
                                        (const float4*)Wv, (ushort4*)xbf);
  proj_kernel<<<dim3(32, 16, 2), 256, 0, stream>>>(xbf, wqbf, wvbf, bq, bv,
                                                   Qh, KVh, KVt);
  attn_kernel<<<1024, 128, 0, stream>>>(Qh, KVh, KVt, out);
}

// Round 11
// 153.010 us; speedup vs baseline: 1.1940x; 1.1940x over previous
//
#include <hip/hip_runtime.h>
#include <hip/hip_bf16.h>
#include <math.h>

// B=2, S=2048, D=1024, H=16, Dh=64.
// Q = x@Wq.T + bq ; KV = x@Wv.T + bv (reference bug: K uses value proj).
// Head split: col -> (ii = col>>4 [dim], h = col&15 [head]).
// out[b, s, h*64 + ii] = attn[b,h,s,ii], fp32.

typedef __bf16 bf16x8 __attribute__((ext_vector_type(8)));
typedef float  f32x4  __attribute__((ext_vector_type(4)));
typedef short  s16x4  __attribute__((ext_vector_type(4)));
typedef unsigned short ushort_t;
typedef unsigned short us8 __attribute__((ext_vector_type(8)));

// 0.125 (1/sqrt(64)) * log2(e): folded into Qh so softmax uses exp2 directly.
#define QSCALE 0.1803368801111204f

__device__ __forceinline__ unsigned short f2bf(float f) {
  unsigned int u = __builtin_bit_cast(unsigned int, f);
  u += 0x7fffu + ((u >> 16) & 1u);  // RNE
  return (unsigned short)(u >> 16);
}

// pack two f32 -> bf16x2 dword (a in low half), round-half-up
__device__ __forceinline__ unsigned int pk2(float a, float b) {
  unsigned int ua = __builtin_bit_cast(unsigned int, a) + 0x8000u;
  unsigned int ub = __builtin_bit_cast(unsigned int, b) + 0x8000u;
  return (ua >> 16) | (ub & 0xffff0000u);
}

// single-instruction pack (RNE): lo -> low half, hi -> high half
__device__ __forceinline__ unsigned int cvtpk(float lo, float hi) {
  unsigned int r;
  asm("v_cvt_pk_bf16_f32 %0, %1, %2" : "=v"(r) : "v"(lo), "v"(hi));
  return r;
}

__device__ __forceinline__ void gl_lds16(const void* g, void* l) {
  __builtin_amdgcn_global_load_lds(
      (const __attribute__((address_space(1))) unsigned int*)g,
      (__attribute__((address_space(3))) unsigned int*)l, 16, 0, 0);
}

__device__ __forceinline__ f32x4 mfma_k32(bf16x8 a, bf16x8 b, f32x4 c) {
  return __builtin_amdgcn_mfma_f32_16x16x32_bf16(a, b, c, 0, 0, 0);
}
// K=16 bf16 MFMA: A k-mapping (quad*4+j) == C/D row mapping (quad*4+r), so the
// exp'd S^T accumulator packs directly into PV A-fragments (no LDS round-trip).
__device__ __forceinline__ f32x4 mfma_k16(s16x4 a, s16x4 b, f32x4 c) {
  return __builtin_amdgcn_mfma_f32_16x16x16bf16_1k(a, b, c, 0, 0, 0);
}

// One launch converts x (1048576 float4), Wq (262144), Wv (262144) into the
// contiguous bf16 region [xbf | wqbf | wvbf] in ws.
__global__ __launch_bounds__(256) void cvt3_kernel(const float4* __restrict__ x,
                                                   const float4* __restrict__ wq,
                                                   const float4* __restrict__ wv,
                                                   ushort4* __restrict__ dst) {
  const int i = blockIdx.x * 256 + threadIdx.x;
  const float4 v = (i < 1048576) ? x[i]
                 : (i < 1310720) ? wq[i - 1048576]
                                 : wv[i - 1310720];
  ushort4 o;
  o.x = f2bf(v.x); o.y = f2bf(v.y); o.z = f2bf(v.z); o.w = f2bf(v.w);
  dst[i] = o;
}

// ---------------- Projection GEMM, head-grouped columns ---------------------------
// (R0 version verbatim — verified passing twice.)
// z=0: Q (scaled). z=1: KV; epilogue also transposes the block's 2-head tile
// through LDS and writes KVt directly.
__global__ __launch_bounds__(256) void proj_kernel(
    const ushort_t* __restrict__ X,     // [4096][1024] bf16
    const ushort_t* __restrict__ Wqm,
    const ushort_t* __restrict__ Wvm,
    const float*    __restrict__ bq,
    const float*    __restrict__ bv,
    ushort_t* __restrict__ Qh,          // [2][16][2048][64] (scaled by QSCALE)
    ushort_t* __restrict__ KVh,         // [2][16][2048][64]
    ushort_t* __restrict__ KVt)         // [2][16][64][2048]
{
  __shared__ __align__(16) unsigned char lds[32768];
  const int tid = threadIdx.x;
  const int w  = tid >> 6;
  const int l  = tid & 63;
  const int lq = l >> 4;      // quad
  const int ll = l & 15;
  const bool isQ = (blockIdx.z == 0);
  const ushort_t* Wmat = isQ ? Wqm : Wvm;
  const float*    bias = isQ ? bq  : bv;
  const int m0 = blockIdx.x * 128;
  const int by = blockIdx.y;
  const int wm = (w & 1) * 64;
  const int wn = (w >> 1) * 64;

  f32x4 acc[4][4] = {};

  for (int k0 = 0; k0 < 1024; k0 += 64) {
    __syncthreads();
#pragma unroll
    for (int t = 0; t < 4; ++t) {
      const int seg = w * 4 + t;
      const int r = seg * 8 + (l >> 3);
      const int cd = (l & 7) ^ (r & 7);
      const int cg = by * 128 + r;                         // logical col
      const int wrow = ((cg & 63) << 4) | (cg >> 6);       // W row for that col
      gl_lds16(X    + (size_t)(m0 + r) * 1024 + k0 + cd * 8, lds + seg * 1024);
      gl_lds16(Wmat + (size_t)wrow * 1024 + k0 + cd * 8, lds + 16384 + seg * 1024);
    }
    __syncthreads();
#pragma unroll
    for (int kb = 0; kb < 2; ++kb) {
      const int kc = kb * 4 + lq;
      bf16x8 af[4], bfr[4];
#pragma unroll
      for (int mi = 0; mi < 4; ++mi) {
        const int m = wm + mi * 16 + ll;
        af[mi] = *(const bf16x8*)(lds + m * 128 + ((kc ^ (m & 7)) * 16));
      }
#pragma unroll
      for (int ni = 0; ni < 4; ++ni) {
        const int n = wn + ni * 16 + ll;
        bfr[ni] = *(const bf16x8*)(lds + 16384 + n * 128 + ((kc ^ (n & 7)) * 16));
      }
#pragma unroll
      for (int mi = 0; mi < 4; ++mi)
#pragma unroll
        for (int ni = 0; ni < 4; ++ni)
          acc[mi][ni] = mfma_k32(af[mi], bfr[ni], acc[mi][ni]);
    }
  }

  const int hl = wn >> 6;               // head-local within block (0/1)
  const int hh = by * 2 + hl;           // global head (wave-uniform)
  const int b  = m0 >> 11;              // batch (block-uniform; 128 | 2048)
  const int sbase = m0 & 2047;

  if (isQ) {
#pragma unroll
    for (int ni = 0; ni < 4; ++ni) {
      const int ii = ni * 16 + ll;
      const float bb = bias[(ii << 4) | hh];
#pragma unroll
      for (int mi = 0; mi < 4; ++mi)
#pragma unroll
        for (int r = 0; r < 4; ++r) {
          const int s = sbase + wm + mi * 16 + lq * 4 + r;
          const float v = acc[mi][ni][r] + bb;
          Qh[(((size_t)(b * 16 + hh)) * 2048 + s) * 64 + ii] = f2bf(v * QSCALE);
        }
    }
  } else {
    __syncthreads();   // staging LDS no longer needed; reuse for transpose
#pragma unroll
    for (int ni = 0; ni < 4; ++ni) {
      const int ii = ni * 16 + ll;
      const float bb = bias[(ii << 4) | hh];
#pragma unroll
      for (int mi = 0; mi < 4; ++mi) {
        const float v0 = acc[mi][ni][0] + bb;
        const float v1 = acc[mi][ni][1] + bb;
        const float v2 = acc[mi][ni][2] + bb;
        const float v3 = acc[mi][ni][3] + bb;
        const unsigned int u01 = pk2(v0, v1);
        const unsigned int u23 = pk2(v2, v3);
        // KVh stores (coalesced per lane in ii)
        const int sl = wm + mi * 16 + lq * 4;
        const size_t kb0 = (((size_t)(b * 16 + hh)) * 2048 + sbase + sl) * 64 + ii;
        KVh[kb0]       = (ushort_t)(u01 & 0xffffu);
        KVh[kb0 + 64]  = (ushort_t)(u01 >> 16);
        KVh[kb0 + 128] = (ushort_t)(u23 & 0xffffu);
        KVh[kb0 + 192] = (ushort_t)(u23 >> 16);
        // LDS transpose write: granule g holds s_loc = 4g..4g+3 for row (hl,ii)
        const int g = (wm >> 2) + mi * 4 + lq;          // 0..31
        const int pc = (g >> 1) ^ ll;
        *(uint2*)(lds + hl * 16384 + ii * 256 + pc * 16 + (g & 1) * 8) =
            make_uint2(u01, u23);
      }
    }
    __syncthreads();
    // Read rows of [hl][ii][s 0..127] and store KVt coalesced (16B per thread)
    const int row = tid >> 1;            // 0..127 -> (hl2, ii2)
    const int hl2 = row >> 6, ii2 = row & 63;
    const int cbase = (tid & 1) * 8;
    ushort_t* dst = KVt + (((size_t)(b * 16 + by * 2 + hl2)) * 64 + ii2) * 2048 + sbase;
#pragma unroll
    for (int cc = 0; cc < 8; ++cc) {
      const int c = cbase + cc;
      const int pc = c ^ (ii2 & 15);
      const us8 v = *(const us8*)(lds + hl2 * 16384 + ii2 * 256 + pc * 16);
      *(us8*)(dst + c * 8) = v;
    }
  }
}

// ---------------- Flash attention: 32q/wave, 2-wave blocks ------------------------
// R15: the R0 baseline kernel BYTE-FOR-BYTE in structure (serial stage ->
// __syncthreads -> compute; verified passing twice), with exactly two pure
// per-lane VALU deltas (both present in R3's passing run):
//   1. pk2 -> cvtpk (v_cvt_pk_bf16_f32: 1 inst/pair vs 5)
//   2. l_run cross-lane reduce deferred to the epilogue (sum is linear)
// No memory op, address, barrier, or layout changes. If this fails, cvtpk
// is convicted as the session's hidden poison and is reverted next round.
// 128 thr / 2 waves; block = 64 q-rows; LDS: K 16KB + Vt 16KB = 32KB.
__global__ __launch_bounds__(128, 2) void attn_kernel(
    const ushort_t* __restrict__ Qh,
    const ushort_t* __restrict__ KVh,
    const ushort_t* __restrict__ KVt,
    float* __restrict__ out)
{
  __shared__ __align__(16) unsigned char sm[32768];
  const int tid = threadIdx.x;
  const int w  = tid >> 6;
  const int l  = tid & 63;
  const int quad = l >> 4;
  const int ll = l & 15;
  const int bid = blockIdx.x;
  const int bh = ((bid & 7) << 2) | (bid >> 8);   // 4 heads per XCD (L2 locality)
  const int qt = (bid >> 3) & 31;
  const int b = bh >> 4, h = bh & 15;
  const int qw = qt * 64 + w * 32;                // this wave's 32 q-rows
  const ushort_t* Qhead  = Qh  + (size_t)bh * (2048 * 64);
  const ushort_t* Khead  = KVh + (size_t)bh * (2048 * 64);
  const ushort_t* Vthead = KVt + (size_t)bh * (64 * 2048);

  // Loop-invariant Q fragments, 2 q-columns (B-operand of S^T: n=q, k=d)
  bf16x8 qf[2][2];
#pragma unroll
  for (int c = 0; c < 2; ++c)
#pragma unroll
    for (int kb = 0; kb < 2; ++kb)
      qf[c][kb] = *(const bf16x8*)(Qhead + (size_t)(qw + c * 16 + ll) * 64 +
                                   kb * 32 + quad * 8);

  f32x4 O[2][4] = {};
  float l_run[2] = {0.f, 0.f};

  for (int kt = 0; kt < 16; ++kt) {
    const int sk0 = kt * 128;
    __syncthreads();                       // previous compute done; LDS reusable
#pragma unroll
    for (int t = 0; t < 8; ++t) {          // K tile [128 keys][64 d], 8 segs/wave
      const int seg = w * 8 + t;
      const int r = seg * 8 + (l >> 3);
      const int cd = (l & 7) ^ (r & 7);
      gl_lds16(Khead + (size_t)(sk0 + r) * 64 + cd * 8, sm + seg * 1024);
    }
#pragma unroll
    for (int t = 0; t < 8; ++t) {          // V^T tile [64 d][128 keys], 8 segs/wave
      const int seg = w * 8 + t;
      const int d = seg * 4 + (l >> 4);
      const int c8 = (l & 15) ^ (d & 15);  // logical 8-key chunk for phys slot l&15
      gl_lds16(Vthead + (size_t)d * 2048 + sk0 + c8 * 8, sm + 16384 + seg * 1024);
    }
    __syncthreads();                       // vmcnt drain (hidden by other blocks)

    // S^T = K @ Q^T : each A-read (K) feeds both q-columns
    f32x4 Sa[2][8] = {};
#pragma unroll
    for (int kb = 0; kb < 2; ++kb) {
      const int kc = kb * 4 + quad;
#pragma unroll
      for (int ni = 0; ni < 8; ++ni) {
        const int n = ni * 16 + ll;
        const bf16x8 ak = *(const bf16x8*)(sm + n * 128 + ((kc ^ (n & 7)) * 16));
        Sa[0][ni] = mfma_k32(ak, qf[0][kb], Sa[0][ni]);
        Sa[1][ni] = mfma_k32(ak, qf[1][kb], Sa[1][ni]);
      }
    }

    // p = exp2(S), pack straight into PV A-fragments (C row map == A k map)
    s16x4 pk[2][8];
#pragma unroll
    for (int c = 0; c < 2; ++c) {
      float ps = 0.f;
#pragma unroll
      for (int ni = 0; ni < 8; ++ni) {
        const float p0 = __builtin_amdgcn_exp2f(Sa[c][ni][0]);
        const float p1 = __builtin_amdgcn_exp2f(Sa[c][ni][1]);
        const float p2 = __builtin_amdgcn_exp2f(Sa[c][ni][2]);
        const float p3 = __builtin_amdgcn_exp2f(Sa[c][ni][3]);
        ps += (p0 + p1) + (p2 + p3);
        const uint2 uu = make_uint2(cvtpk(p0, p1), cvtpk(p2, p3));
        pk[c][ni] = __builtin_bit_cast(s16x4, uu);
      }
      l_run[c] += ps;   // cross-lane reduce deferred to the epilogue (linear)
    }

    // O += P @ V : each B-read (V, b64, 2-way max) feeds both q-columns
#pragma unroll
    for (int ni = 0; ni < 8; ++ni) {
      const int cb = 2 * ni + (quad >> 1);           // logical 8-key chunk
#pragma unroll
      for (int no = 0; no < 4; ++no) {
        const int row = no * 16 + ll;                // d
        const s16x4 bv = *(const s16x4*)(sm + 16384 + row * 256 +
                                         ((cb ^ ll) * 16) + (quad & 1) * 8);
        O[0][no] = mfma_k16(pk[0][ni], bv, O[0][no]);
        O[1][no] = mfma_k16(pk[1][ni], bv, O[1][no]);
      }
    }
  }

#pragma unroll
  for (int c = 0; c < 2; ++c) {
    float s = l_run[c];
    s += __shfl_xor(s, 16);
    s += __shfl_xor(s, 32);
    const float inv = 1.f / s;
    float invr[4];
#pragma unroll
    for (int r = 0; r < 4; ++r)
      invr[r] = __shfl(inv, (l & 48) + ((l & 48) >> 2) + r);  // q=quad*4+r's sum
    float* op = out + ((size_t)(b * 2048) + qw + c * 16) * 1024 + h * 64;
#pragma unroll
    for (int no = 0; no < 4; ++no)
#pragma unroll
      for (int r = 0; r < 4; ++r) {
        const int q = quad * 4 + r;
        op[(size_t)q * 1024 + no * 16 + ll] = O[c][no][r] * invr[r];
      }
  }
}

extern "C" void kernel_launch(void* const* d_in, const int* in_sizes, int n_in,
                              void* d_out, int out_size, void* d_ws, size_t ws_size,
                              hipStream_t stream) {
  const float* x  = (const float*)d_in[0];
  const float* Wq = (const float*)d_in[1];
  const float* bq = (const float*)d_in[2];
  const float* Wv = (const float*)d_in[3];
  const float* bv = (const float*)d_in[4];
  float* out = (float*)d_out;
  char* ws = (char*)d_ws;

  ushort_t* xbf  = (ushort_t*)(ws);              //  8 MB
  ushort_t* wqbf = (ushort_t*)(ws + 8388608);    //  2 MB
  ushort_t* wvbf = (ushort_t*)(ws + 10485760);   //  2 MB
  ushort_t* Qh   = (ushort_t*)(ws + 12582912);   //  8 MB [2][16][2048][64]
  ushort_t* KVh  = (ushort_t*)(ws + 20971520);   //  8 MB [2][16][2048][64]
  ushort_t* KVt  = (ushort_t*)(ws + 29360128);   //  8 MB [2][16][64][2048]

  cvt3_kernel<<<6144, 256, 0, stream>>>((const float4*)x, (const float4*)Wq,
                                        (const float4*)Wv, (ushort4*)xbf);
  proj_kernel<<<dim3(32, 8, 2), 256, 0, stream>>>(xbf, wqbf, wvbf, bq, bv,
                                                  Qh, KVh, KVt);
  attn_kernel<<<1024, 128, 0, stream>>>(Qh, KVh, KVt, out);
}

// Round 13
// 149.518 us; speedup vs baseline: 1.2219x; 1.0234x over previous
//
#include <hip/hip_runtime.h>
#include <hip/hip_bf16.h>
#include <math.h>

// B=2, S=2048, D=1024, H=16, Dh=64.
// Q = x@Wq.T + bq ; KV = x@Wv.T + bv (reference bug: K uses value proj).
// Head split: col -> (ii = col>>4 [dim], h = col&15 [head]).
// out[b, s, h*64 + ii] = attn[b,h,s,ii], fp32.

typedef __bf16 bf16x8 __attribute__((ext_vector_type(8)));
typedef float  f32x4  __attribute__((ext_vector_type(4)));
typedef short  s16x4  __attribute__((ext_vector_type(4)));
typedef unsigned short ushort_t;
typedef unsigned short us8 __attribute__((ext_vector_type(8)));

// 0.125 (1/sqrt(64)) * log2(e): folded into Qh so softmax uses exp2 directly.
#define QSCALE 0.1803368801111204f

__device__ __forceinline__ unsigned short f2bf(float f) {
  unsigned int u = __builtin_bit_cast(unsigned int, f);
  u += 0x7fffu + ((u >> 16) & 1u);  // RNE
  return (unsigned short)(u >> 16);
}

// pack two f32 -> bf16x2 dword (a in low half), round-half-up
__device__ __forceinline__ unsigned int pk2(float a, float b) {
  unsigned int ua = __builtin_bit_cast(unsigned int, a) + 0x8000u;
  unsigned int ub = __builtin_bit_cast(unsigned int, b) + 0x8000u;
  return (ua >> 16) | (ub & 0xffff0000u);
}

// single-instruction pack (RNE): lo -> low half, hi -> high half
__device__ __forceinline__ unsigned int cvtpk(float lo, float hi) {
  unsigned int r;
  asm("v_cvt_pk_bf16_f32 %0, %1, %2" : "=v"(r) : "v"(lo), "v"(hi));
  return r;
}

__device__ __forceinline__ void gl_lds16(const void* g, void* l) {
  __builtin_amdgcn_global_load_lds(
      (const __attribute__((address_space(1))) unsigned int*)g,
      (__attribute__((address_space(3))) unsigned int*)l, 16, 0, 0);
}

__device__ __forceinline__ f32x4 mfma_k32(bf16x8 a, bf16x8 b, f32x4 c) {
  return __builtin_amdgcn_mfma_f32_16x16x32_bf16(a, b, c, 0, 0, 0);
}
// K=16 bf16 MFMA: A k-mapping (quad*4+j) == C/D row mapping (quad*4+r), so the
// exp'd S^T accumulator packs directly into PV A-fragments (no LDS round-trip).
__device__ __forceinline__ f32x4 mfma_k16(s16x4 a, s16x4 b, f32x4 c) {
  return __builtin_amdgcn_mfma_f32_16x16x16bf16_1k(a, b, c, 0, 0, 0);
}

// One launch converts x (1048576 float4), Wq (262144), Wv (262144) into the
// contiguous bf16 region [xbf | wqbf | wvbf] in ws.
__global__ __launch_bounds__(256) void cvt3_kernel(const float4* __restrict__ x,
                                                   const float4* __restrict__ wq,
                                                   const float4* __restrict__ wv,
                                                   ushort4* __restrict__ dst) {
  const int i = blockIdx.x * 256 + threadIdx.x;
  const float4 v = (i < 1048576) ? x[i]
                 : (i < 1310720) ? wq[i - 1048576]
                                 : wv[i - 1310720];
  ushort4 o;
  o.x = f2bf(v.x); o.y = f2bf(v.y); o.z = f2bf(v.z); o.w = f2bf(v.w);
  dst[i] = o;
}

// ---------------- Projection GEMM, head-grouped columns ---------------------------
// R4 version VERBATIM (empirically verified: R4's full run passed the absmax
// check, so this kernel's Qh/KVh/KVt outputs are correct). BN=64 (one head
// per block) -> grid 32x16x2 = 1024 blocks = 4 blocks/CU (R0's BN=128 runs
// 512 = 2/CU and is latency-starved).
__global__ __launch_bounds__(256) void proj_kernel(
    const ushort_t* __restrict__ X,     // [4096][1024] bf16
    const ushort_t* __restrict__ Wqm,
    const ushort_t* __restrict__ Wvm,
    const float*    __restrict__ bq,
    const float*    __restrict__ bv,
    ushort_t* __restrict__ Qh,          // [2][16][2048][64] (scaled by QSCALE)
    ushort_t* __restrict__ KVh,         // [2][16][2048][64]
    ushort_t* __restrict__ KVt)         // [2][16][64][2048]
{
  __shared__ __align__(16) unsigned char lds[24576];   // A 16KB | B 8KB
  const int tid = threadIdx.x;
  const int w  = tid >> 6;
  const int l  = tid & 63;
  const int lq = l >> 4;      // quad
  const int ll = l & 15;
  const bool isQ = (blockIdx.z == 0);
  const ushort_t* Wmat = isQ ? Wqm : Wvm;
  const float*    bias = isQ ? bq  : bv;
  const int m0 = blockIdx.x * 128;
  const int by = blockIdx.y;          // head 0..15
  const int wm = w * 32;              // wave's 32 output rows

  f32x4 acc[2][4] = {};

  for (int k0 = 0; k0 < 1024; k0 += 64) {
    __syncthreads();
#pragma unroll
    for (int t = 0; t < 4; ++t) {     // A tile: 128 rows x 64 k, 16 segs
      const int seg = w * 4 + t;
      const int r = seg * 8 + (l >> 3);
      const int cd = (l & 7) ^ (r & 7);
      gl_lds16(X + (size_t)(m0 + r) * 1024 + k0 + cd * 8, lds + seg * 1024);
    }
#pragma unroll
    for (int t = 0; t < 2; ++t) {     // B tile: 64 cols (head by) x 64 k, 8 segs
      const int seg = w * 2 + t;
      const int r = seg * 8 + (l >> 3);            // ii = r (one head)
      const int cd = (l & 7) ^ (r & 7);
      const int wrow = (r << 4) | by;              // W row for col (ii=r, h=by)
      gl_lds16(Wmat + (size_t)wrow * 1024 + k0 + cd * 8, lds + 16384 + seg * 1024);
    }
    __syncthreads();
#pragma unroll
    for (int kb = 0; kb < 2; ++kb) {
      const int kc = kb * 4 + lq;
      bf16x8 af[2], bfr[4];
#pragma unroll
      for (int mi = 0; mi < 2; ++mi) {
        const int m = wm + mi * 16 + ll;
        af[mi] = *(const bf16x8*)(lds + m * 128 + ((kc ^ (m & 7)) * 16));
      }
#pragma unroll
      for (int ni = 0; ni < 4; ++ni) {
        const int n = ni * 16 + ll;
        bfr[ni] = *(const bf16x8*)(lds + 16384 + n * 128 + ((kc ^ (n & 7)) * 16));
      }
#pragma unroll
      for (int mi = 0; mi < 2; ++mi)
#pragma unroll
        for (int ni = 0; ni < 4; ++ni)
          acc[mi][ni] = mfma_k32(af[mi], bfr[ni], acc[mi][ni]);
    }
  }

  const int hh = by;                  // global head (block-uniform)
  const int b  = m0 >> 11;            // batch (block-uniform; 128 | 2048)
  const int sbase = m0 & 2047;

  if (isQ) {
#pragma unroll
    for (int ni = 0; ni < 4; ++ni) {
      const int ii = ni * 16 + ll;
      const float bb = bias[(ii << 4) | hh];
#pragma unroll
      for (int mi = 0; mi < 2; ++mi)
#pragma unroll
        for (int r = 0; r < 4; ++r) {
          const int s = sbase + wm + mi * 16 + lq * 4 + r;
          const float v = acc[mi][ni][r] + bb;
          Qh[(((size_t)(b * 16 + hh)) * 2048 + s) * 64 + ii] = f2bf(v * QSCALE);
        }
    }
  } else {
    __syncthreads();   // staging LDS no longer needed; reuse for transpose
#pragma unroll
    for (int ni = 0; ni < 4; ++ni) {
      const int ii = ni * 16 + ll;
      const float bb = bias[(ii << 4) | hh];
#pragma unroll
      for (int mi = 0; mi < 2; ++mi) {
        const float v0 = acc[mi][ni][0] + bb;
        const float v1 = acc[mi][ni][1] + bb;
        const float v2 = acc[mi][ni][2] + bb;
        const float v3 = acc[mi][ni][3] + bb;
        const unsigned int u01 = pk2(v0, v1);
        const unsigned int u23 = pk2(v2, v3);
        // KVh stores (coalesced per lane in ii)
        const int sl = wm + mi * 16 + lq * 4;
        const size_t kb0 = (((size_t)(b * 16 + hh)) * 2048 + sbase + sl) * 64 + ii;
        KVh[kb0]       = (ushort_t)(u01 & 0xffffu);
        KVh[kb0 + 64]  = (ushort_t)(u01 >> 16);
        KVh[kb0 + 128] = (ushort_t)(u23 & 0xffffu);
        KVh[kb0 + 192] = (ushort_t)(u23 >> 16);
        // LDS transpose write: granule g holds s_loc = 4g..4g+3 for row ii
        const int g = w * 8 + mi * 4 + lq;              // 0..31
        const int pc = (g >> 1) ^ ll;
        *(uint2*)(lds + ii * 256 + pc * 16 + (g & 1) * 8) =
            make_uint2(u01, u23);
      }
    }
    __syncthreads();
    // Read rows of [ii][s 0..127] and store KVt coalesced (16B per thread)
    const int ii2 = tid >> 2;            // 0..63
    const int cbase = (tid & 3) * 4;
    ushort_t* dst = KVt + (((size_t)(b * 16 + by)) * 64 + ii2) * 2048 + sbase;
#pragma unroll
    for (int cc = 0; cc < 4; ++cc) {
      const int c = cbase + cc;
      const int pc = c ^ (ii2 & 15);
      const us8 v = *(const us8*)(lds + ii2 * 256 + pc * 16);
      *(us8*)(dst + c * 8) = v;
    }
  }
}

// ---------------- Flash attention: 32q/wave, 2-wave blocks ------------------------
// R15 kernel VERBATIM (verified passing at 57.6-58.2us): serial stage ->
// __syncthreads -> compute, single 32KB buffer, cvtpk pack, deferred l_run
// reduce. The 2-wave serial skeleton is the only attn structure that passes
// (3/3); all structural deviations failed. No changes this round.
// 128 thr / 2 waves; block = 64 q-rows; LDS: K 16KB + Vt 16KB = 32KB.
__global__ __launch_bounds__(128, 2) void attn_kernel(
    const ushort_t* __restrict__ Qh,
    const ushort_t* __restrict__ KVh,
    const ushort_t* __restrict__ KVt,
    float* __restrict__ out)
{
  __shared__ __align__(16) unsigned char sm[32768];
  const int tid = threadIdx.x;
  const int w  = tid >> 6;
  const int l  = tid & 63;
  const int quad = l >> 4;
  const int ll = l & 15;
  const int bid = blockIdx.x;
  const int bh = ((bid & 7) << 2) | (bid >> 8);   // 4 heads per XCD (L2 locality)
  const int qt = (bid >> 3) & 31;
  const int b = bh >> 4, h = bh & 15;
  const int qw = qt * 64 + w * 32;                // this wave's 32 q-rows
  const ushort_t* Qhead  = Qh  + (size_t)bh * (2048 * 64);
  const ushort_t* Khead  = KVh + (size_t)bh * (2048 * 64);
  const ushort_t* Vthead = KVt + (size_t)bh * (64 * 2048);

  // Loop-invariant Q fragments, 2 q-columns (B-operand of S^T: n=q, k=d)
  bf16x8 qf[2][2];
#pragma unroll
  for (int c = 0; c < 2; ++c)
#pragma unroll
    for (int kb = 0; kb < 2; ++kb)
      qf[c][kb] = *(const bf16x8*)(Qhead + (size_t)(qw + c * 16 + ll) * 64 +
                                   kb * 32 + quad * 8);

  f32x4 O[2][4] = {};
  float l_run[2] = {0.f, 0.f};

  for (int kt = 0; kt < 16; ++kt) {
    const int sk0 = kt * 128;
    __syncthreads();                       // previous compute done; LDS reusable
#pragma unroll
    for (int t = 0; t < 8; ++t) {          // K tile [128 keys][64 d], 8 segs/wave
      const int seg = w * 8 + t;
      const int r = seg * 8 + (l >> 3);
      const int cd = (l & 7) ^ (r & 7);
      gl_lds16(Khead + (size_t)(sk0 + r) * 64 + cd * 8, sm + seg * 1024);
    }
#pragma unroll
    for (int t = 0; t < 8; ++t) {          // V^T tile [64 d][128 keys], 8 segs/wave
      const int seg = w * 8 + t;
      const int d = seg * 4 + (l >> 4);
      const int c8 = (l & 15) ^ (d & 15);  // logical 8-key chunk for phys slot l&15
      gl_lds16(Vthead + (size_t)d * 2048 + sk0 + c8 * 8, sm + 16384 + seg * 1024);
    }
    __syncthreads();                       // vmcnt drain (hidden by other blocks)

    // S^T = K @ Q^T : each A-read (K) feeds both q-columns
    f32x4 Sa[2][8] = {};
#pragma unroll
    for (int kb = 0; kb < 2; ++kb) {
      const int kc = kb * 4 + quad;
#pragma unroll
      for (int ni = 0; ni < 8; ++ni) {
        const int n = ni * 16 + ll;
        const bf16x8 ak = *(const bf16x8*)(sm + n * 128 + ((kc ^ (n & 7)) * 16));
        Sa[0][ni] = mfma_k32(ak, qf[0][kb], Sa[0][ni]);
        Sa[1][ni] = mfma_k32(ak, qf[1][kb], Sa[1][ni]);
      }
    }

    // p = exp2(S), pack straight into PV A-fragments (C row map == A k map)
    s16x4 pk[2][8];
#pragma unroll
    for (int c = 0; c < 2; ++c) {
      float ps = 0.f;
#pragma unroll
      for (int ni = 0; ni < 8; ++ni) {
        const float p0 = __builtin_amdgcn_exp2f(Sa[c][ni][0]);
        const float p1 = __builtin_amdgcn_exp2f(Sa[c][ni][1]);
        const float p2 = __builtin_amdgcn_exp2f(Sa[c][ni][2]);
        const float p3 = __builtin_amdgcn_exp2f(Sa[c][ni][3]);
        ps += (p0 + p1) + (p2 + p3);
        const uint2 uu = make_uint2(cvtpk(p0, p1), cvtpk(p2, p3));
        pk[c][ni] = __builtin_bit_cast(s16x4, uu);
      }
      l_run[c] += ps;   // cross-lane reduce deferred to the epilogue (linear)
    }

    // O += P @ V : each B-read (V, b64, 2-way max) feeds both q-columns
#pragma unroll
    for (int ni = 0; ni < 8; ++ni) {
      const int cb = 2 * ni + (quad >> 1);           // logical 8-key chunk
#pragma unroll
      for (int no = 0; no < 4; ++no) {
        const int row = no * 16 + ll;                // d
        const s16x4 bv = *(const s16x4*)(sm + 16384 + row * 256 +
                                         ((cb ^ ll) * 16) + (quad & 1) * 8);
        O[0][no] = mfma_k16(pk[0][ni], bv, O[0][no]);
        O[1][no] = mfma_k16(pk[1][ni], bv, O[1][no]);
      }
    }
  }

#pragma unroll
  for (int c = 0; c < 2; ++c) {
    float s = l_run[c];
    s += __shfl_xor(s, 16);
    s += __shfl_xor(s, 32);
    const float inv = 1.f / s;
    float invr[4];
#pragma unroll
    for (int r = 0; r < 4; ++r)
      invr[r] = __shfl(inv, (l & 48) + ((l & 48) >> 2) + r);  // q=quad*4+r's sum
    float* op = out + ((size_t)(b * 2048) + qw + c * 16) * 1024 + h * 64;
#pragma unroll
    for (int no = 0; no < 4; ++no)
#pragma unroll
      for (int r = 0; r < 4; ++r) {
        const int q = quad * 4 + r;
        op[(size_t)q * 1024 + no * 16 + ll] = O[c][no][r] * invr[r];
      }
  }
}

extern "C" void kernel_launch(void* const* d_in, const int* in_sizes, int n_in,
                              void* d_out, int out_size, void* d_ws, size_t ws_size,
                              hipStream_t stream) {
  const float* x  = (const float*)d_in[0];
  const float* Wq = (const float*)d_in[1];
  const float* bq = (const float*)d_in[2];
  const float* Wv = (const float*)d_in[3];
  const float* bv = (const float*)d_in[4];
  float* out = (float*)d_out;
  char* ws = (char*)d_ws;

  ushort_t* xbf  = (ushort_t*)(ws);              //  8 MB
  ushort_t* wqbf = (ushort_t*)(ws + 8388608);    //  2 MB
  ushort_t* wvbf = (ushort_t*)(ws + 10485760);   //  2 MB
  ushort_t* Qh   = (ushort_t*)(ws + 12582912);   //  8 MB [2][16][2048][64]
  ushort_t* KVh  = (ushort_t*)(ws + 20971520);   //  8 MB [2][16][2048][64]
  ushort_t* KVt  = (ushort_t*)(ws + 29360128);   //  8 MB [2][16][64][2048]

  cvt3_kernel<<<6144, 256, 0, stream>>>((const float4*)x, (const float4*)Wq,
                                        (const float4*)Wv, (ushort4*)xbf);
  proj_kernel<<<dim3(32, 16, 2), 256, 0, stream>>>(xbf, wqbf, wvbf, bq, bv,
                                                   Qh, KVh, KVt);
  attn_kernel<<<1024, 128, 0, stream>>>(Qh, KVh, KVt, out);
}